// Round 1
// baseline (237.047 us; speedup 1.0000x reference)
//
#include <hip/hip_runtime.h>
#include <hip/hip_bf16.h>
#include <stdint.h>
#include <stddef.h>

typedef __bf16 bf16;
typedef __bf16 bf16x4 __attribute__((ext_vector_type(4)));
typedef __bf16 bf16x8 __attribute__((ext_vector_type(8)));
typedef float  f32x4  __attribute__((ext_vector_type(4)));

// ---------------------------------------------------------------- helpers
__device__ __forceinline__ void gld_lds16(const void* gptr, void* lptr) {
    // async global->LDS, 16B per lane; LDS dest must be wave-uniform base + lane*16
    __builtin_amdgcn_global_load_lds(
        (const __attribute__((address_space(1))) unsigned int*)gptr,
        (__attribute__((address_space(3))) unsigned int*)lptr,
        16, 0, 0);
}

// ---------------------------------------------------------------- casts / zero
__global__ void cast_f32_bf16(const float* __restrict__ src, bf16* __restrict__ dst, int n) {
    int i = (blockIdx.x * 256 + threadIdx.x) * 4;
    if (i < n) {
        float4 v = *(const float4*)(src + i);
        bf16x4 o = { (bf16)v.x, (bf16)v.y, (bf16)v.z, (bf16)v.w };
        *(bf16x4*)(dst + i) = o;
    }
}

__global__ void zero_out(float* __restrict__ out, int n) {
    int i = blockIdx.x * 64 + threadIdx.x;
    if (i < n) out[i] = 0.f;
}

// ---------------------------------------------------------------- m97-style NT GEMM
// C[M,N] bf16 = A[M,Kd] * B[N,Kd]^T, all bf16, fp32 accumulate.
// BM=BN=128, BK=32, 256 threads (4 waves, 2x2 wave grid, 64x64 per wave).
__global__ void gemm_bt(const bf16* __restrict__ A, const bf16* __restrict__ Bm,
                        bf16* __restrict__ C, int Mrows, int Ncols, int Kd) {
    __shared__ __align__(16) bf16 As[128 * 32];
    __shared__ __align__(16) bf16 Bs[128 * 32];
    const int t = threadIdx.x;
    const int w = t >> 6, l = t & 63;
    const int wm = (w >> 1) * 64, wn = (w & 1) * 64;
    const int tile_m = blockIdx.x * 128;
    const int tile_n = blockIdx.y * 128;

    f32x4 acc[4][4];
#pragma unroll
    for (int i = 0; i < 4; i++)
#pragma unroll
        for (int j = 0; j < 4; j++)
#pragma unroll
            for (int q = 0; q < 4; q++) acc[i][j][q] = 0.f;

    const int row_a = t >> 2;     // 0..63
    const int seg   = t & 3;      // 16B segment within 64B row

    for (int k0 = 0; k0 < Kd; k0 += 32) {
#pragma unroll
        for (int i = 0; i < 2; i++) {
            int r = i * 64 + row_a;
            gld_lds16(A  + (size_t)(tile_m + r) * Kd + k0 + seg * 8, As + (i * 256 + t) * 8);
            gld_lds16(Bm + (size_t)(tile_n + r) * Kd + k0 + seg * 8, Bs + (i * 256 + t) * 8);
        }
        __builtin_amdgcn_s_waitcnt(0);
        __syncthreads();

        const int fr = l & 15;
        const int fk = (l >> 4) * 8;
        bf16x8 af[4], bfr[4];
#pragma unroll
        for (int i = 0; i < 4; i++) {
            af[i]  = *(const bf16x8*)(As + (wm + i * 16 + fr) * 32 + fk);
            bfr[i] = *(const bf16x8*)(Bs + (wn + i * 16 + fr) * 32 + fk);
        }
#pragma unroll
        for (int i = 0; i < 4; i++)
#pragma unroll
            for (int j = 0; j < 4; j++)
                acc[i][j] = __builtin_amdgcn_mfma_f32_16x16x32_bf16(af[i], bfr[j], acc[i][j], 0, 0, 0);
        __syncthreads();
    }

    // epilogue: C/D layout col=lane&15, row=(lane>>4)*4+reg  [m89-verified]
    const int cr = (l >> 4) * 4, cc = l & 15;
#pragma unroll
    for (int i = 0; i < 4; i++)
#pragma unroll
        for (int j = 0; j < 4; j++)
#pragma unroll
            for (int r = 0; r < 4; r++) {
                int row = tile_m + wm + i * 16 + cr + r;
                int col = tile_n + wn + j * 16 + cc;
                C[(size_t)row * Ncols + col] = (bf16)acc[i][j][r];
            }
}

// ---------------------------------------------------------------- fused attention lse
// QK: [8192, 1536] bf16; cols 0..767 = q(h*64+z), 768..1535 = k(h*64+z)
// grid (qt=8, h=12, b=8), block 256. Each block: 128 q-rows, full K=1024 loop.
// energy += -8 * sum_rows log( sum_k exp(0.125 * QK^T) )
__global__ void attn_energy(const bf16* __restrict__ QK, float* __restrict__ out) {
    __shared__ __align__(16) bf16 Qs[8 * 128 * 8];   // [zseg][qrow][8] 16KB
    __shared__ __align__(16) bf16 Ks[8 * 256 * 8];   // [zseg][krow][8] 32KB
    __shared__ float wpart[4];
    const int t = threadIdx.x, w = t >> 6, l = t & 63;
    const int qt = blockIdx.x, h = blockIdx.y, b = blockIdx.z;
    const size_t qbase = ((size_t)b * 1024 + qt * 128) * 1536 + h * 64;
    const size_t kcol  = 768 + h * 64;

    // stage Q tile (fragment-major: [zseg][row][8])
#pragma unroll
    for (int i = 0; i < 4; i++) {
        int c = i * 256 + t;          // 0..1023
        int row = c >> 3, zs = c & 7;
        *(uint4*)(Qs + zs * 1024 + row * 8) =
            *(const uint4*)(QK + qbase + (size_t)row * 1536 + zs * 8);
    }
    __syncthreads();

    const int fr = l & 15, fg = l >> 4;
    bf16x8 af[2][2];
#pragma unroll
    for (int mi = 0; mi < 2; mi++)
#pragma unroll
        for (int ks = 0; ks < 2; ks++)
            af[mi][ks] = *(const bf16x8*)(Qs + (ks * 4 + fg) * 1024 + (w * 32 + mi * 16 + fr) * 8);

    float rs[2][4] = {};
    for (int kc = 0; kc < 4; kc++) {
        __syncthreads();   // protect Ks before restaging
#pragma unroll
        for (int i = 0; i < 8; i++) {
            int c = i * 256 + t;      // 0..2047
            int row = c >> 3, zs = c & 7;
            *(uint4*)(Ks + zs * 2048 + row * 8) =
                *(const uint4*)(QK + ((size_t)b * 1024 + kc * 256 + row) * 1536 + kcol + zs * 8);
        }
        __syncthreads();
#pragma unroll
        for (int nt = 0; nt < 16; nt++) {
            bf16x8 b0 = *(const bf16x8*)(Ks + (0 * 4 + fg) * 2048 + (nt * 16 + fr) * 8);
            bf16x8 b1 = *(const bf16x8*)(Ks + (1 * 4 + fg) * 2048 + (nt * 16 + fr) * 8);
#pragma unroll
            for (int mi = 0; mi < 2; mi++) {
                f32x4 acc;
#pragma unroll
                for (int q = 0; q < 4; q++) acc[q] = 0.f;
                acc = __builtin_amdgcn_mfma_f32_16x16x32_bf16(af[mi][0], b0, acc, 0, 0, 0);
                acc = __builtin_amdgcn_mfma_f32_16x16x32_bf16(af[mi][1], b1, acc, 0, 0, 0);
#pragma unroll
                for (int r = 0; r < 4; r++) rs[mi][r] += __expf(0.125f * acc[r]);
            }
        }
    }

    // cols of a row live in the 16 lanes with same (l>>4): butterfly over lane&15
    float e = 0.f;
#pragma unroll
    for (int mi = 0; mi < 2; mi++)
#pragma unroll
        for (int r = 0; r < 4; r++) {
            float v = rs[mi][r];
            v += __shfl_xor(v, 1, 16);
            v += __shfl_xor(v, 2, 16);
            v += __shfl_xor(v, 4, 16);
            v += __shfl_xor(v, 8, 16);
            if ((l & 15) == 0) e += __logf(v);
        }
    e += __shfl_down(e, 32, 64);
    e += __shfl_down(e, 16, 64);
    if (l == 0) wpart[w] = e;
    __syncthreads();
    if (t == 0) atomicAdd(out, -8.f * (wpart[0] + wpart[1] + wpart[2] + wpart[3]));
}

// ---------------------------------------------------------------- Hopfield lse
// H: [8192, 3072] bf16 (unscaled g@W^T). energy += -(1/beta)*sum_rows log(sum_m exp(beta*H))
__global__ void hn_energy(const bf16* __restrict__ Hm, const float* __restrict__ beta,
                          float* __restrict__ out) {
    __shared__ float wpart[4];
    const int t = threadIdx.x, w = t >> 6, l = t & 63;
    const int row = blockIdx.x * 4 + w;
    const float sc = beta[0];
    const bf16* p = Hm + (size_t)row * 3072;
    float s = 0.f;
#pragma unroll
    for (int i = 0; i < 6; i++) {
        bf16x8 v = *(const bf16x8*)(p + i * 512 + l * 8);
#pragma unroll
        for (int j = 0; j < 8; j++) s += __expf(sc * (float)v[j]);
    }
    for (int o = 32; o > 0; o >>= 1) s += __shfl_down(s, o, 64);
    if (l == 0) wpart[w] = __logf(s);
    __syncthreads();
    if (t == 0) atomicAdd(out, (-1.f / sc) * (wpart[0] + wpart[1] + wpart[2] + wpart[3]));
}

// ---------------------------------------------------------------- launch
extern "C" void kernel_launch(void* const* d_in, const int* in_sizes, int n_in,
                              void* d_out, int out_size, void* d_ws, size_t ws_size,
                              hipStream_t stream) {
    const float* g    = (const float*)d_in[0];   // [8,1024,768]
    const float* wq   = (const float*)d_in[1];   // [12,64,768]
    const float* wk   = (const float*)d_in[2];   // [12,64,768]
    const float* w_hn = (const float*)d_in[3];   // [3072,768]
    const float* beta = (const float*)d_in[4];   // [1]
    float* out = (float*)d_out;

    char* ws = (char*)d_ws;
    bf16* g_bf   = (bf16*)(ws);                          // 12,582,912 B
    bf16* wqk_bf = (bf16*)(ws + 12582912);               //  2,359,296 B
    bf16* whn_bf = (bf16*)(ws + 14942208);               //  4,718,592 B
    bf16* qk     = (bf16*)(ws + 19660800);               // 25,165,824 B
    bf16* Hmat   = (bf16*)(ws + 44826624);               // 50,331,648 B  (end ~95.2 MB)

    zero_out<<<1, 64, 0, stream>>>(out, out_size);
    cast_f32_bf16<<<6291456 / 4 / 256, 256, 0, stream>>>(g, g_bf, 6291456);
    cast_f32_bf16<<<589824 / 4 / 256, 256, 0, stream>>>(wq, wqk_bf, 589824);
    cast_f32_bf16<<<589824 / 4 / 256, 256, 0, stream>>>(wk, wqk_bf + 589824, 589824);
    cast_f32_bf16<<<2359296 / 4 / 256, 256, 0, stream>>>(w_hn, whn_bf, 2359296);

    dim3 g1(64, 12), g2(64, 24);
    gemm_bt<<<g1, 256, 0, stream>>>(g_bf, wqk_bf, qk, 8192, 1536, 768);   // q|k proj
    gemm_bt<<<g2, 256, 0, stream>>>(g_bf, whn_bf, Hmat, 8192, 3072, 768); // hopfield

    dim3 ga(8, 12, 8);
    attn_energy<<<ga, 256, 0, stream>>>(qk, out);
    hn_energy<<<2048, 256, 0, stream>>>(Hmat, beta, out);
}

// Round 2
// 217.338 us; speedup vs baseline: 1.0907x; 1.0907x over previous
//
#include <hip/hip_runtime.h>
#include <hip/hip_bf16.h>
#include <stdint.h>
#include <stddef.h>

typedef __bf16 bf16;
typedef __bf16 bf16x4 __attribute__((ext_vector_type(4)));
typedef __bf16 bf16x8 __attribute__((ext_vector_type(8)));
typedef float  f32x4  __attribute__((ext_vector_type(4)));

// ---------------------------------------------------------------- helpers
__device__ __forceinline__ void gld_lds16(const void* gptr, void* lptr) {
    __builtin_amdgcn_global_load_lds(
        (const __attribute__((address_space(1))) unsigned int*)gptr,
        (__attribute__((address_space(3))) unsigned int*)lptr,
        16, 0, 0);
}

// ---------------------------------------------------------------- casts / zero
__global__ void cast_f32_bf16(const float* __restrict__ src, bf16* __restrict__ dst, int n) {
    int i = (blockIdx.x * 256 + threadIdx.x) * 4;
    if (i < n) {
        float4 v = *(const float4*)(src + i);
        bf16x4 o = { (bf16)v.x, (bf16)v.y, (bf16)v.z, (bf16)v.w };
        *(bf16x4*)(dst + i) = o;
    }
}

__global__ void zero_f32(float* __restrict__ p, int n) {
    int i = blockIdx.x * 256 + threadIdx.x;
    if (i < n) p[i] = 0.f;
}

// ---------------------------------------------------------------- fused NT GEMM
// C_full[M, 4608] = A[M,768] * Wcat[4608,768]^T  (bf16 in, fp32 acc)
// cols [0,1536): store bf16 to qk (attention consumes it)
// cols [1536,4608): Hopfield — fold into per-row exp-sum (atomicAdd rowsum)
// BM=BN=128, BK=32, 256 threads (4 waves, 2x2 wave grid, 64x64 per wave).
__global__ void gemm_fused(const bf16* __restrict__ A, const bf16* __restrict__ Bm,
                           bf16* __restrict__ qk, float* __restrict__ rowsum,
                           const float* __restrict__ beta_p, int Kd) {
    __shared__ __align__(16) bf16 As[128 * 32];
    __shared__ __align__(16) bf16 Bs[128 * 32];
    const int t = threadIdx.x;
    const int w = t >> 6, l = t & 63;
    const int wm = (w >> 1) * 64, wn = (w & 1) * 64;
    const int tile_m = blockIdx.x * 128;
    const int tile_n = blockIdx.y * 128;

    f32x4 acc[4][4];
#pragma unroll
    for (int i = 0; i < 4; i++)
#pragma unroll
        for (int j = 0; j < 4; j++)
#pragma unroll
            for (int q = 0; q < 4; q++) acc[i][j][q] = 0.f;

    const int row_a = t >> 2;     // 0..63
    const int seg   = t & 3;      // 16B segment within 64B row

    for (int k0 = 0; k0 < Kd; k0 += 32) {
#pragma unroll
        for (int i = 0; i < 2; i++) {
            int r = i * 64 + row_a;
            gld_lds16(A  + (size_t)(tile_m + r) * Kd + k0 + seg * 8, As + (i * 256 + t) * 8);
            gld_lds16(Bm + (size_t)(tile_n + r) * Kd + k0 + seg * 8, Bs + (i * 256 + t) * 8);
        }
        __builtin_amdgcn_s_waitcnt(0);
        __syncthreads();

        const int fr = l & 15;
        const int fk = (l >> 4) * 8;
        bf16x8 af[4], bfr[4];
#pragma unroll
        for (int i = 0; i < 4; i++) {
            af[i]  = *(const bf16x8*)(As + (wm + i * 16 + fr) * 32 + fk);
            bfr[i] = *(const bf16x8*)(Bs + (wn + i * 16 + fr) * 32 + fk);
        }
#pragma unroll
        for (int i = 0; i < 4; i++)
#pragma unroll
            for (int j = 0; j < 4; j++)
                acc[i][j] = __builtin_amdgcn_mfma_f32_16x16x32_bf16(af[i], bfr[j], acc[i][j], 0, 0, 0);
        __syncthreads();
    }

    // C/D layout: col=lane&15, row=(lane>>4)*4+reg  [m89-verified]
    const int cr = (l >> 4) * 4, cc = l & 15;

    if (tile_n < 1536) {
        // attention q|k projection: store bf16 tile to qk [8192,1536]
#pragma unroll
        for (int i = 0; i < 4; i++)
#pragma unroll
            for (int j = 0; j < 4; j++)
#pragma unroll
                for (int r = 0; r < 4; r++) {
                    int row = tile_m + wm + i * 16 + cr + r;
                    int col = tile_n + wn + j * 16 + cc;
                    qk[(size_t)row * 1536 + col] = (bf16)acc[i][j][r];
                }
    } else {
        // Hopfield: rowsum[row] += sum_cols exp(beta * acc)
        const float sc = beta_p[0];
#pragma unroll
        for (int i = 0; i < 4; i++)
#pragma unroll
            for (int r = 0; r < 4; r++) {
                float s = 0.f;
#pragma unroll
                for (int j = 0; j < 4; j++) s += __expf(sc * acc[i][j][r]);
                // reduce across the 16 lanes holding this row's cols
                s += __shfl_xor(s, 1, 16);
                s += __shfl_xor(s, 2, 16);
                s += __shfl_xor(s, 4, 16);
                s += __shfl_xor(s, 8, 16);
                if ((l & 15) == 0)
                    atomicAdd(&rowsum[tile_m + wm + i * 16 + cr + r], s);
            }
    }
}

// ---------------------------------------------------------------- hopfield finalize
__global__ void hn_finalize(const float* __restrict__ rowsum, const float* __restrict__ beta_p,
                            float* __restrict__ out) {
    __shared__ float wpart[4];
    const int t = threadIdx.x, w = t >> 6, l = t & 63;
    float s = 0.f;
    for (int i = t; i < 8192; i += 256) s += __logf(rowsum[i]);
    for (int o = 32; o > 0; o >>= 1) s += __shfl_down(s, o, 64);
    if (l == 0) wpart[w] = s;
    __syncthreads();
    if (t == 0) atomicAdd(out, (-1.f / beta_p[0]) * (wpart[0] + wpart[1] + wpart[2] + wpart[3]));
}

// ---------------------------------------------------------------- fused attention lse
// QK: [8192, 1536] bf16; cols 0..767 = q(h*64+z), 768..1535 = k(h*64+z)
// grid (qt=8, h=12, b=8), block 256. Each block: 128 q-rows, full K=1024 loop.
// energy += -8 * sum_rows log( sum_k exp(0.125 * QK^T) )
__global__ void attn_energy(const bf16* __restrict__ QK, float* __restrict__ out) {
    __shared__ __align__(16) bf16 Qs[8 * 128 * 8];   // [zseg][qrow][8] 16KB
    __shared__ __align__(16) bf16 Ks[8 * 256 * 8];   // [zseg][krow][8] 32KB
    __shared__ float wpart[4];
    const int t = threadIdx.x, w = t >> 6, l = t & 63;
    const int qt = blockIdx.x, h = blockIdx.y, b = blockIdx.z;
    const size_t qbase = ((size_t)b * 1024 + qt * 128) * 1536 + h * 64;
    const size_t kcol  = 768 + h * 64;

#pragma unroll
    for (int i = 0; i < 4; i++) {
        int c = i * 256 + t;          // 0..1023
        int row = c >> 3, zs = c & 7;
        *(uint4*)(Qs + zs * 1024 + row * 8) =
            *(const uint4*)(QK + qbase + (size_t)row * 1536 + zs * 8);
    }
    __syncthreads();

    const int fr = l & 15, fg = l >> 4;
    bf16x8 af[2][2];
#pragma unroll
    for (int mi = 0; mi < 2; mi++)
#pragma unroll
        for (int ks = 0; ks < 2; ks++)
            af[mi][ks] = *(const bf16x8*)(Qs + (ks * 4 + fg) * 1024 + (w * 32 + mi * 16 + fr) * 8);

    float rs[2][4] = {};
    for (int kc = 0; kc < 4; kc++) {
        __syncthreads();
#pragma unroll
        for (int i = 0; i < 8; i++) {
            int c = i * 256 + t;      // 0..2047
            int row = c >> 3, zs = c & 7;
            *(uint4*)(Ks + zs * 2048 + row * 8) =
                *(const uint4*)(QK + ((size_t)b * 1024 + kc * 256 + row) * 1536 + kcol + zs * 8);
        }
        __syncthreads();
#pragma unroll
        for (int nt = 0; nt < 16; nt++) {
            bf16x8 b0 = *(const bf16x8*)(Ks + (0 * 4 + fg) * 2048 + (nt * 16 + fr) * 8);
            bf16x8 b1 = *(const bf16x8*)(Ks + (1 * 4 + fg) * 2048 + (nt * 16 + fr) * 8);
#pragma unroll
            for (int mi = 0; mi < 2; mi++) {
                f32x4 acc;
#pragma unroll
                for (int q = 0; q < 4; q++) acc[q] = 0.f;
                acc = __builtin_amdgcn_mfma_f32_16x16x32_bf16(af[mi][0], b0, acc, 0, 0, 0);
                acc = __builtin_amdgcn_mfma_f32_16x16x32_bf16(af[mi][1], b1, acc, 0, 0, 0);
#pragma unroll
                for (int r = 0; r < 4; r++) rs[mi][r] += __expf(0.125f * acc[r]);
            }
        }
    }

    float e = 0.f;
#pragma unroll
    for (int mi = 0; mi < 2; mi++)
#pragma unroll
        for (int r = 0; r < 4; r++) {
            float v = rs[mi][r];
            v += __shfl_xor(v, 1, 16);
            v += __shfl_xor(v, 2, 16);
            v += __shfl_xor(v, 4, 16);
            v += __shfl_xor(v, 8, 16);
            if ((l & 15) == 0) e += __logf(v);
        }
    e += __shfl_down(e, 32, 64);
    e += __shfl_down(e, 16, 64);
    if (l == 0) wpart[w] = e;
    __syncthreads();
    if (t == 0) atomicAdd(out, -8.f * (wpart[0] + wpart[1] + wpart[2] + wpart[3]));
}

// ---------------------------------------------------------------- launch
extern "C" void kernel_launch(void* const* d_in, const int* in_sizes, int n_in,
                              void* d_out, int out_size, void* d_ws, size_t ws_size,
                              hipStream_t stream) {
    const float* g    = (const float*)d_in[0];   // [8,1024,768]
    const float* wq   = (const float*)d_in[1];   // [12,64,768]
    const float* wk   = (const float*)d_in[2];   // [12,64,768]
    const float* w_hn = (const float*)d_in[3];   // [3072,768]
    const float* beta = (const float*)d_in[4];   // [1]
    float* out = (float*)d_out;

    char* ws = (char*)d_ws;
    bf16*  g_bf   = (bf16*)(ws);                          // 12,582,912 B
    bf16*  Wcat   = (bf16*)(ws + 12582912);               //  7,077,888 B (4608 x 768)
    bf16*  qk     = (bf16*)(ws + 19660800);               // 25,165,824 B
    float* rowsum = (float*)(ws + 44826624);              //     32,768 B (8192 f32)

    zero_f32<<<1, 64, 0, stream>>>(out, out_size);
    zero_f32<<<32, 256, 0, stream>>>(rowsum, 8192);
    cast_f32_bf16<<<6291456 / 4 / 256, 256, 0, stream>>>(g, g_bf, 6291456);
    cast_f32_bf16<<<589824 / 4 / 256, 256, 0, stream>>>(wq, Wcat, 589824);
    cast_f32_bf16<<<589824 / 4 / 256, 256, 0, stream>>>(wk, Wcat + 589824, 589824);
    cast_f32_bf16<<<2359296 / 4 / 256, 256, 0, stream>>>(w_hn, Wcat + 1179648, 2359296);

    dim3 gg(64, 36);   // 8192/128 x 4608/128
    gemm_fused<<<gg, 256, 0, stream>>>(g_bf, Wcat, qk, rowsum, beta, 768);

    dim3 ga(8, 12, 8);
    attn_energy<<<ga, 256, 0, stream>>>(qk, out);
    hn_finalize<<<1, 256, 0, stream>>>(rowsum, beta, out);
}